// Round 1
// baseline (356.756 us; speedup 1.0000x reference)
//
#include <hip/hip_runtime.h>

#define BINS 256
#define NLO (-4.0f)
#define NHI (4.0f)
#define SCALE 32.0f   // BINS / (HI - LO)

constexpr int TPB = 256;   // 4 waves/block

__device__ __forceinline__ void bin_one(float v, unsigned* h) {
    // Match reference exactly: idx = floor((x - LO) * scale); min(idx, 255);
    // valid iff LO <= x <= HI (NaN fails both compares -> discarded).
    float t = (v - NLO) * SCALE;
    int b = (int)floorf(t);
    b = b > (BINS - 1) ? (BINS - 1) : b;
    if (v >= NLO && v <= NHI) {
        atomicAdd(&h[b], 1u);   // ds_atomic_add, wave-private copy
    }
}

__global__ __launch_bounds__(TPB, 4) void hist_partial(
        const float4* __restrict__ x4, int n4,
        const float* __restrict__ x, int n,
        unsigned* __restrict__ partials) {
    __shared__ unsigned lds[4 * BINS];   // one 256-bin histogram per wave
    const int tid = threadIdx.x;

    #pragma unroll
    for (int i = tid; i < 4 * BINS; i += TPB) lds[i] = 0;
    __syncthreads();

    unsigned* h = lds + (tid >> 6) * BINS;   // wave-private histogram

    const int stride = gridDim.x * TPB;
    int i = blockIdx.x * TPB + tid;

    // 4x unrolled grid-stride: 4 outstanding dwordx4 loads per thread
    for (; i + 3 * stride < n4; i += 4 * stride) {
        float4 a = x4[i];
        float4 b = x4[i + stride];
        float4 c = x4[i + 2 * stride];
        float4 d = x4[i + 3 * stride];
        bin_one(a.x, h); bin_one(a.y, h); bin_one(a.z, h); bin_one(a.w, h);
        bin_one(b.x, h); bin_one(b.y, h); bin_one(b.z, h); bin_one(b.w, h);
        bin_one(c.x, h); bin_one(c.y, h); bin_one(c.z, h); bin_one(c.w, h);
        bin_one(d.x, h); bin_one(d.y, h); bin_one(d.z, h); bin_one(d.w, h);
    }
    for (; i < n4; i += stride) {
        float4 a = x4[i];
        bin_one(a.x, h); bin_one(a.y, h); bin_one(a.z, h); bin_one(a.w, h);
    }
    // scalar tail (n not divisible by 4) — handled by block 0
    if (blockIdx.x == 0) {
        int tail = n - n4 * 4;
        if (tid < tail) bin_one(x[n4 * 4 + tid], h);
    }

    __syncthreads();

    // merge 4 wave copies; coalesced partial write (no global atomics)
    unsigned total = lds[tid] + lds[BINS + tid] + lds[2 * BINS + tid] + lds[3 * BINS + tid];
    partials[(size_t)blockIdx.x * BINS + tid] = total;
}

__global__ void hist_reduce(const unsigned* __restrict__ partials, int P,
                            float* __restrict__ out) {
    const int bin = blockIdx.x;    // 256 blocks, one per bin
    const int lane = threadIdx.x;  // 64 threads = 1 wave
    unsigned s = 0;
    for (int p = lane; p < P; p += 64)
        s += partials[(size_t)p * BINS + bin];
    #pragma unroll
    for (int off = 32; off > 0; off >>= 1)
        s += __shfl_down(s, off);
    if (lane == 0) {
        float f = (float)s;
        out[bin] = f;           // h
        out[BINS + bin] = f;    // h (tuple returns (h, h))
    }
}

extern "C" void kernel_launch(void* const* d_in, const int* in_sizes, int n_in,
                              void* d_out, int out_size, void* d_ws, size_t ws_size,
                              hipStream_t stream) {
    const float* x = (const float*)d_in[0];
    const int n = in_sizes[0];
    const int n4 = n / 4;

    // partials live in d_ws: P blocks x 256 u32
    int P = (int)(ws_size / (BINS * sizeof(unsigned)));
    if (P > 1024) P = 1024;
    if (P < 1) P = 1;

    unsigned* partials = (unsigned*)d_ws;
    float* out = (float*)d_out;

    hist_partial<<<P, TPB, 0, stream>>>((const float4*)x, n4, x, n, partials);
    hist_reduce<<<BINS, 64, 0, stream>>>(partials, P, out);
}

// Round 2
// 355.134 us; speedup vs baseline: 1.0046x; 1.0046x over previous
//
#include <hip/hip_runtime.h>

#define BINS 256
#define HSTRIDE 257          // +1 pad per wave-histogram to rotate banks
constexpr int TPB  = 256;    // 4 waves/block
constexpr int GRID = 2048;   // 8 blocks/CU

typedef float f32x4 __attribute__((ext_vector_type(4)));

__device__ __forceinline__ void bin_one(float v, unsigned* h) {
    // Reference: idx = floor((x - (-4)) * 32); idx = min(idx, 255);
    // valid iff -4 <= x <= 4 (NaN fails -> discard). Branchless: route
    // invalid lanes to dump slot 256 so the ds_atomic is unconditional.
    float t = (v + 4.0f) * 32.0f;
    int b = (int)floorf(t);
    b = b > (BINS - 1) ? (BINS - 1) : b;
    bool valid = (v >= -4.0f) && (v <= 4.0f);
    int idx = valid ? b : BINS;
    atomicAdd(&h[idx], 1u);
}

__global__ void zero_out(float* __restrict__ out) {
    int i = blockIdx.x * blockDim.x + threadIdx.x;
    if (i < 2 * BINS) out[i] = 0.0f;
}

__global__ __launch_bounds__(TPB) void hist_main(
        const f32x4* __restrict__ x4, int n4,
        const float* __restrict__ x, int n,
        float* __restrict__ out) {
    __shared__ unsigned lds[4 * HSTRIDE];   // one padded histogram per wave
    const int tid = threadIdx.x;

    #pragma unroll
    for (int i = tid; i < 4 * HSTRIDE; i += TPB) lds[i] = 0;
    __syncthreads();

    unsigned* h = lds + (tid >> 6) * HSTRIDE;   // wave-private histogram

    const int stride = gridDim.x * TPB;
    int i = blockIdx.x * TPB + tid;

    // 8 nontemporal dwordx4 loads in flight per thread (streamed once —
    // keep it out of L2), then 32 bin updates.
    for (; i + 7 * stride < n4; i += 8 * stride) {
        f32x4 v[8];
        #pragma unroll
        for (int j = 0; j < 8; ++j)
            v[j] = __builtin_nontemporal_load(&x4[i + j * stride]);
        #pragma unroll
        for (int j = 0; j < 8; ++j) {
            bin_one(v[j].x, h); bin_one(v[j].y, h);
            bin_one(v[j].z, h); bin_one(v[j].w, h);
        }
    }
    for (; i < n4; i += stride) {
        f32x4 a = __builtin_nontemporal_load(&x4[i]);
        bin_one(a.x, h); bin_one(a.y, h); bin_one(a.z, h); bin_one(a.w, h);
    }
    if (blockIdx.x == 0) {          // scalar tail (n % 4), none for n = 2^26
        int tail = n - n4 * 4;
        if (tid < tail) bin_one(x[n4 * 4 + tid], h);
    }

    __syncthreads();

    // Merge the 4 wave copies; one float atomic per bin per output half.
    // Counts are integers < 2^24 -> every f32 add is exact -> deterministic.
    unsigned total = lds[tid] + lds[HSTRIDE + tid]
                   + lds[2 * HSTRIDE + tid] + lds[3 * HSTRIDE + tid];
    float f = (float)total;
    atomicAdd(&out[tid], f);
    atomicAdd(&out[BINS + tid], f);
}

extern "C" void kernel_launch(void* const* d_in, const int* in_sizes, int n_in,
                              void* d_out, int out_size, void* d_ws, size_t ws_size,
                              hipStream_t stream) {
    const float* x = (const float*)d_in[0];
    const int n = in_sizes[0];
    const int n4 = n / 4;
    float* out = (float*)d_out;

    zero_out<<<1, 2 * BINS, 0, stream>>>(out);
    hist_main<<<GRID, TPB, 0, stream>>>((const f32x4*)x, n4, x, n, out);
}